// Round 14
// baseline (246.372 us; speedup 1.0000x reference)
//
#include <hip/hip_runtime.h>

#define N_NODES 100000
#define N_EDGES 1600000
#define D 128
#define N_STRIPS (N_NODES / 32)     // 3125

#define BSH   9                     // bucket = col >> 9 (512 nodes/bucket)
#define NBKT  196                   // ceil(100000 / 512)
#define P_BLK 256                   // one block per CU; EPB = 6250 exactly
#define EPB   (N_EDGES / P_BLK)
#define ARENA 9216                  // per-bucket arena slots (mean 8163 + ~12 sigma)

typedef __bf16 bf16x4 __attribute__((ext_vector_type(4)));
typedef __bf16 bf16x8 __attribute__((ext_vector_type(8)));
typedef float  f32x4  __attribute__((ext_vector_type(4)));

__device__ __forceinline__ void acc8(float (&a)[8], uint4 v) {
    a[0] += __uint_as_float(v.x << 16);
    a[1] += __uint_as_float(v.x & 0xFFFF0000u);
    a[2] += __uint_as_float(v.y << 16);
    a[3] += __uint_as_float(v.y & 0xFFFF0000u);
    a[4] += __uint_as_float(v.z << 16);
    a[5] += __uint_as_float(v.z & 0xFFFF0000u);
    a[6] += __uint_as_float(v.w << 16);
    a[7] += __uint_as_float(v.w & 0xFFFF0000u);
}

// generic (rare) per-node gather: 4 edges per VMEM step
__device__ __forceinline__ void gather_node(const int* __restrict__ srcs,
                                            int s, int n,
                                            const unsigned char* hbase,
                                            size_t boff, int lane, int q,
                                            float (&acc)[8]) {
    for (int base = 0; base < n; base += 64) {
        int m = n - base; if (m > 64) m = 64;
        int src_l = (lane < m) ? srcs[s + base + lane] : 0;
        int i = 0;
        for (; i + 4 <= m; i += 4) {
            int sj = __shfl(src_l, i + q);
            uint4 v = *(const uint4*)(hbase + ((size_t)sj + boff));
            acc8(acc, v);
        }
        if (i < m) {
            int sj = __shfl(src_l, i + q);
            if (q < m - i) {
                uint4 v = *(const uint4*)(hbase + ((size_t)sj + boff));
                acc8(acc, v);
            }
        }
    }
}

// ---- K1: MERGED partition. 256 blocks (1/CU, all co-resident by construction).
// Phase 1: LDS-sort slice by bucket, reserve arena windows (1 global atomic per
// (block,bucket)), coalesced bucket-run writes. Device-scope arrival barrier.
// Phase 2: blocks 0..NBKT-1 fine-sort one bucket each (LDS-cached), emitting
// deg/dis/start and rewriting the arena in place as srcs byte offsets; block
// NBKT casts W. ----
__global__ __launch_bounds__(1024) void k_part(const int* __restrict__ row,
                                               const int* __restrict__ col,
                                               const float4* __restrict__ w4,
                                               int* __restrict__ gcnt,      // [256] cursors; gcnt[256] = done
                                               unsigned* __restrict__ arena,
                                               bf16x4* __restrict__ wb4,
                                               int* __restrict__ deg,
                                               float* __restrict__ dis,
                                               int* __restrict__ start) {
    __shared__ unsigned smem[23040];           // 92,160 B -> 1 block/CU
    int b = blockIdx.x, t = threadIdx.x;
    int* done = gcnt + 256;

    // ---------------- phase 1: scatter ----------------
    {
        int*            rec  = (int*)smem;                     // [6250]
        unsigned short* kb   = (unsigned short*)(smem + 6272); // [6250]
        int*            srt  = (int*)(smem + 9408);            // [6250]
        int*            dofp = (int*)(smem + 15680);           // [6250]
        int*            lh   = (int*)(smem + 21952);           // [256]
        int*            sc   = lh + 256;
        int*            cur  = sc + 256;
        int*            dofk = cur + 256;

        if (t < 256) lh[t] = 0;
        __syncthreads();
        int e0 = b * EPB;
        for (int i = t; i < EPB; i += 1024) {
            int r = row[e0 + i], c = col[e0 + i];
            int k = c >> BSH;
            rec[i] = (r << BSH) | (c & ((1 << BSH) - 1));
            kb[i]  = (unsigned short)k;
            atomicAdd(&lh[k], 1);
        }
        __syncthreads();
        int v = 0;
        if (t < 256) { v = lh[t]; sc[t] = v; }
        __syncthreads();
        for (int off = 1; off < 256; off <<= 1) {
            int u = 0;
            if (t < 256 && t >= off) u = sc[t - off];
            __syncthreads();
            if (t < 256) sc[t] += u;
            __syncthreads();
        }
        if (t < 256) {
            int excl = sc[t] - v;              // local exclusive base
            sc[t]  = excl;
            cur[t] = 0;
            int base = (t < NBKT && v > 0) ? atomicAdd(&gcnt[t], v) : 0;
            dofk[t] = t * ARENA + base - excl; // global dst = local pos + dofk
        }
        __syncthreads();
        for (int i = t; i < EPB; i += 1024) {
            int k = kb[i];
            int p = sc[k] + atomicAdd(&cur[k], 1);
            srt[p]  = rec[i];
            dofp[p] = dofk[k];
        }
        __syncthreads();
        for (int i = t; i < EPB; i += 1024) {
            unsigned dst = (unsigned)(i + dofp[i]);
            if (dst < (unsigned)(NBKT * ARENA))         // defensive (12-sigma)
                arena[dst] = (unsigned)srt[i];
        }
    }

    // ---------------- device-scope arrival barrier ----------------
    __syncthreads();
    if (t == 0) {
        __threadfence();                                       // release block's stores
        __hip_atomic_fetch_add(done, 1, __ATOMIC_ACQ_REL, __HIP_MEMORY_SCOPE_AGENT);
        while (__hip_atomic_load(done, __ATOMIC_ACQUIRE, __HIP_MEMORY_SCOPE_AGENT) < P_BLK) {}
    }
    __syncthreads();

    // ---------------- phase 2: fine sort / W cast ----------------
    if (b < NBKT) {
        unsigned* cache = smem;                  // [9216]
        int*      fh    = (int*)(smem + 9216);   // [512]
        int*      fsc   = (int*)(smem + 9728);   // [512]
        int cnt = gcnt[b]; if (cnt > ARENA) cnt = ARENA;
        int gs = b * ARENA;
        if (t < 512) fh[t] = 0;
        __syncthreads();
        for (int i = t; i < cnt; i += 1024) {
            unsigned r = arena[gs + i];
            cache[i] = r;
            atomicAdd(&fh[r & 511], 1);
        }
        __syncthreads();
        int v = 0;
        if (t < 512) { v = fh[t]; fsc[t] = v; }
        __syncthreads();
        for (int off = 1; off < 512; off <<= 1) {
            int u = 0;
            if (t < 512 && t >= off) u = fsc[t - off];
            __syncthreads();
            if (t < 512) fsc[t] += u;
            __syncthreads();
        }
        if (t < 512) {
            int excl = fsc[t] - v;                // exclusive scan value
            int node = (b << BSH) + t;
            if (node < N_NODES) {
                deg[node]   = v;
                dis[node]   = rsqrtf((float)v + 1.0f);
                start[node] = gs + excl;
            }
            fh[t] = excl;                         // -> cursors
        }
        __syncthreads();
        for (int i = t; i < cnt; i += 1024) {
            unsigned r = cache[i];
            int pos = atomicAdd(&fh[r & 511], 1);
            arena[gs + pos] = (r >> BSH) << 8;    // row * 256 = byte offset into hb
        }
    } else if (b == NBKT) {
        for (int i = t; i < (D * D) / 4; i += 1024) {
            float4 u = w4[i];
            bf16x4 p;
            p[0] = (__bf16)u.x; p[1] = (__bf16)u.y;
            p[2] = (__bf16)u.z; p[3] = (__bf16)u.w;
            wb4[i] = p;
        }
    }
}

// ---- K2: transform-first: hb[row] = bf16( (x @ W^T)[row] * dis[row] ) ----
__global__ __launch_bounds__(256) void k_hx(const float* __restrict__ x,
                                            const __bf16* __restrict__ wb,
                                            const float* __restrict__ dis,
                                            __bf16* __restrict__ hb) {
    int wave = threadIdx.x >> 6;
    int lane = threadIdx.x & 63;
    int strip = blockIdx.x * 4 + wave;
    if (strip >= N_STRIPS) return;
    int m0 = strip * 32;
    int l15 = lane & 15;
    int kq  = lane >> 4;

    bf16x8 a[2][4];
    #pragma unroll
    for (int mt = 0; mt < 2; ++mt) {
        const float* ap = x + (size_t)(m0 + mt * 16 + l15) * D + kq * 8;
        #pragma unroll
        for (int ks = 0; ks < 4; ++ks) {
            float4 lo = *(const float4*)(ap + ks * 32);
            float4 hi = *(const float4*)(ap + ks * 32 + 4);
            bf16x8 t;
            t[0] = (__bf16)lo.x; t[1] = (__bf16)lo.y;
            t[2] = (__bf16)lo.z; t[3] = (__bf16)lo.w;
            t[4] = (__bf16)hi.x; t[5] = (__bf16)hi.y;
            t[6] = (__bf16)hi.z; t[7] = (__bf16)hi.w;
            a[mt][ks] = t;
        }
    }

    f32x4 acc[2][8] = {};
    #pragma unroll
    for (int ks = 0; ks < 4; ++ks) {
        #pragma unroll
        for (int nt = 0; nt < 8; ++nt) {
            bf16x8 b = *(const bf16x8*)(wb + (size_t)(nt * 16 + l15) * D + ks * 32 + kq * 8);
            acc[0][nt] = __builtin_amdgcn_mfma_f32_16x16x32_bf16(a[0][ks], b, acc[0][nt], 0, 0, 0);
            acc[1][nt] = __builtin_amdgcn_mfma_f32_16x16x32_bf16(a[1][ks], b, acc[1][nt], 0, 0, 0);
        }
    }

    float dsv[2][4];
    #pragma unroll
    for (int mt = 0; mt < 2; ++mt)
        #pragma unroll
        for (int r = 0; r < 4; ++r)
            dsv[mt][r] = dis[m0 + mt * 16 + kq * 4 + r];

    #pragma unroll
    for (int nt = 0; nt < 8; ++nt) {
        int colj = nt * 16 + l15;
        #pragma unroll
        for (int mt = 0; mt < 2; ++mt) {
            #pragma unroll
            for (int r = 0; r < 4; ++r) {
                int rowi = m0 + mt * 16 + kq * 4 + r;
                hb[(size_t)rowi * D + colj] = (__bf16)(acc[mt][nt][r] * dsv[mt][r]);
            }
        }
    }
}

// ---- K3: gather-aggregate, TWO nodes per wave; 16 lanes x dwordx4 per row,
// 4 rows per VMEM instruction per node. Fast path deg<=64; generic fallback. ----
__global__ __launch_bounds__(256) void k_aggregate(const int* __restrict__ srcs,
                                                   const int* __restrict__ start,
                                                   const int* __restrict__ deg,
                                                   const __bf16* __restrict__ hb,
                                                   const float* __restrict__ dis,
                                                   const float* __restrict__ bias,
                                                   float* __restrict__ out) {
    int wid = (blockIdx.x * 256 + threadIdx.x) >> 6;
    int nodeA = wid * 2;
    if (nodeA >= N_NODES) return;
    int nodeB = nodeA + 1;                 // N_NODES even -> always valid
    int lane = threadIdx.x & 63;
    int li = lane & 15;                    // 16B slot within row
    int q  = lane >> 4;                    // quarter
    const unsigned char* hbase = (const unsigned char*)hb;
    size_t boff = (size_t)li * 16;

    int sA = start[nodeA], nA = deg[nodeA];
    int sB = start[nodeB], nB = deg[nodeB];
    float dA = dis[nodeA], dB = dis[nodeB];

    uint4 selfA = *(const uint4*)(hbase + ((size_t)nodeA * 256 + boff));
    uint4 selfB = *(const uint4*)(hbase + ((size_t)nodeB * 256 + boff));

    float accA[8] = {0.f, 0.f, 0.f, 0.f, 0.f, 0.f, 0.f, 0.f};
    float accB[8] = {0.f, 0.f, 0.f, 0.f, 0.f, 0.f, 0.f, 0.f};

    if (nA <= 64 && nB <= 64) {
        int srcA = (lane < nA) ? srcs[sA + lane] : 0;   // byte offsets
        int srcB = (lane < nB) ? srcs[sB + lane] : 0;
        int nmax = nA > nB ? nA : nB;
        #pragma unroll
        for (int i = 0; i < 64; i += 16) {
            if (i >= nmax) break;
            int svA[4], svB[4];
            #pragma unroll
            for (int j = 0; j < 4; ++j) {
                svA[j] = __shfl(srcA, i + 4 * j + q);
                svB[j] = __shfl(srcB, i + 4 * j + q);
            }
            uint4 avA[4], avB[4];
            if (i < nA) {
                #pragma unroll
                for (int j = 0; j < 4; ++j)
                    avA[j] = *(const uint4*)(hbase + ((size_t)svA[j] + boff));
            }
            if (i < nB) {
                #pragma unroll
                for (int j = 0; j < 4; ++j)
                    avB[j] = *(const uint4*)(hbase + ((size_t)svB[j] + boff));
            }
            if (i < nA) {
                #pragma unroll
                for (int j = 0; j < 4; ++j)
                    if (i + 4 * j + q < nA) acc8(accA, avA[j]);
            }
            if (i < nB) {
                #pragma unroll
                for (int j = 0; j < 4; ++j)
                    if (i + 4 * j + q < nB) acc8(accB, avB[j]);
            }
        }
    } else {
        gather_node(srcs, sA, nA, hbase, boff, lane, q, accA);
        gather_node(srcs, sB, nB, hbase, boff, lane, q, accB);
    }

    // combine the four quarters
    #pragma unroll
    for (int k = 0; k < 8; ++k) {
        accA[k] += __shfl_xor(accA[k], 16);
        accA[k] += __shfl_xor(accA[k], 32);
        accB[k] += __shfl_xor(accB[k], 16);
        accB[k] += __shfl_xor(accB[k], 32);
    }

    if (q == 0) {
        // self-loop terms (hb already prescaled by dis[node])
        acc8(accA, selfA);
        acc8(accB, selfB);

        float4 b0 = *(const float4*)(bias + li * 8);
        float4 b1 = *(const float4*)(bias + li * 8 + 4);
        float4 r0, r1;
        r0.x = fmaxf(accA[0] * dA + b0.x, 0.f);
        r0.y = fmaxf(accA[1] * dA + b0.y, 0.f);
        r0.z = fmaxf(accA[2] * dA + b0.z, 0.f);
        r0.w = fmaxf(accA[3] * dA + b0.w, 0.f);
        r1.x = fmaxf(accA[4] * dA + b1.x, 0.f);
        r1.y = fmaxf(accA[5] * dA + b1.y, 0.f);
        r1.z = fmaxf(accA[6] * dA + b1.z, 0.f);
        r1.w = fmaxf(accA[7] * dA + b1.w, 0.f);
        *(float4*)(out + (size_t)nodeA * D + li * 8)     = r0;
        *(float4*)(out + (size_t)nodeA * D + li * 8 + 4) = r1;

        r0.x = fmaxf(accB[0] * dB + b0.x, 0.f);
        r0.y = fmaxf(accB[1] * dB + b0.y, 0.f);
        r0.z = fmaxf(accB[2] * dB + b0.z, 0.f);
        r0.w = fmaxf(accB[3] * dB + b0.w, 0.f);
        r1.x = fmaxf(accB[4] * dB + b1.x, 0.f);
        r1.y = fmaxf(accB[5] * dB + b1.y, 0.f);
        r1.z = fmaxf(accB[6] * dB + b1.z, 0.f);
        r1.w = fmaxf(accB[7] * dB + b1.w, 0.f);
        *(float4*)(out + (size_t)nodeB * D + li * 8)     = r0;
        *(float4*)(out + (size_t)nodeB * D + li * 8 + 4) = r1;
    }
}

extern "C" void kernel_launch(void* const* d_in, const int* in_sizes, int n_in,
                              void* d_out, int out_size, void* d_ws, size_t ws_size,
                              hipStream_t stream) {
    const float* x    = (const float*)d_in[0];
    const int*   ei   = (const int*)d_in[1];    // [2, E]: row then col
    const float* w    = (const float*)d_in[2];
    const float* bias = (const float*)d_in[3];
    float* out = (float*)d_out;

    char* ws = (char*)d_ws;
    int*      deg    = (int*)ws;              ws += N_NODES * 4;
    float*    dis    = (float*)ws;            ws += N_NODES * 4;
    int*      start  = (int*)ws;              ws += N_NODES * 4;
    int*      gcnt   = (int*)ws;              ws += 512 * 4;   // [256] cursors + done + pad
    __bf16*   wb     = (__bf16*)ws;           ws += D * D * 2;
    unsigned* arena  = (unsigned*)ws;         ws += (size_t)NBKT * ARENA * 4;  // grec -> srcs in place
    __bf16*   hb     = (__bf16*)ws;           // N_NODES * D * 2 = 25.6 MB

    const int* row = ei;
    const int* col = ei + N_EDGES;

    hipMemsetAsync(gcnt, 0, 512 * 4, stream);
    k_part     <<<P_BLK, 1024, 0, stream>>>(row, col, (const float4*)w, gcnt, arena,
                                            (bf16x4*)wb, deg, dis, start);
    k_hx       <<<(N_STRIPS + 3) / 4, 256, 0, stream>>>(x, wb, dis, hb);
    k_aggregate<<<(N_NODES / 2 * 64) / 256, 256, 0, stream>>>((const int*)arena, start, deg, hb, dis, bias, out);
}